// Round 10
// baseline (1191.094 us; speedup 1.0000x reference)
//
#include <hip/hip_runtime.h>
#include <math.h>

#define M_SEQ 11520   // B*N
#define NNODE 360
#define NB    32
#define TT    64
#define NQ    6       // decode: nodes per lane (single 64-lane wave per block)

// GRU/feat/adj path: libm-accurate (feeds the precision-fragile argmax).
__device__ __forceinline__ float fsig(float x)  { return 1.0f / (1.0f + expf(-x)); }
__device__ __forceinline__ float ftanh(float x) { return tanhf(x); }
// Decode path: post-argmax, fast hardware exp (safe: absmax 3.8e-6, R7/R9).
__device__ __forceinline__ float fsigd(float x)  { return 1.0f / (1.0f + __expf(-x)); }
__device__ __forceinline__ float ftanhd(float x) { return 1.0f - 2.0f / (__expf(2.0f * x) + 1.0f); }

// ---------------- JAX threefry2x32, key=(0,42), partitionable, bits=y0^y1 ----
__device__ __forceinline__ unsigned rotl32(unsigned x, int n) { return (x << n) | (x >> (32 - n)); }

__device__ __forceinline__ void tf2x32(unsigned& x0, unsigned& x1)
{
    const unsigned k0 = 0u, k1 = 42u, k2 = 0u ^ 42u ^ 0x1BD11BDAu;
    x0 += k0; x1 += k1;
#define R4(a,b,c,d) \
    x0 += x1; x1 = rotl32(x1,a); x1 ^= x0; \
    x0 += x1; x1 = rotl32(x1,b); x1 ^= x0; \
    x0 += x1; x1 = rotl32(x1,c); x1 ^= x0; \
    x0 += x1; x1 = rotl32(x1,d); x1 ^= x0;
    R4(13,15,26,6)   x0 += k1; x1 += k2 + 1u;
    R4(17,29,16,24)  x0 += k2; x1 += k0 + 2u;
    R4(13,15,26,6)   x0 += k0; x1 += k1 + 3u;
    R4(17,29,16,24)  x0 += k1; x1 += k2 + 4u;
    R4(13,15,26,6)   x0 += k2; x1 += k0 + 5u;
#undef R4
}

__device__ __forceinline__ float jax_uniform(unsigned idx)
{
    unsigned x0 = 0u, x1 = idx;
    tf2x32(x0, x1);
    unsigned bits = x0 ^ x1;          // VERIFIED R5
    return __uint_as_float((bits >> 9) | 0x3f800000u) - 1.0f;
}

// broadcast within aligned 8-lane group via static-pattern ds_swizzle.
template<int K>
__device__ __forceinline__ void swz_fma(float h, const float* w0, const float* w1,
                                        const float* w2, float& g0, float& g1, float& g2)
{
    float hk = __int_as_float(
        __builtin_amdgcn_ds_swizzle(__float_as_int(h), (K << 5) | 0x18));
    g0 += hk * w0[K];
    g1 += hk * w1[K];
    g2 += hk * w2[K];
    if constexpr (K < 7)
        swz_fma<K + 1>(h, w0, w1, w2, g0, g1, g2);
}

// ---------------- fused bidirectional GRU layer -----------------------------
template<int I>
__global__ __launch_bounds__(256) void gru_fused(
    const float* __restrict__ x,    // (M,64,I)
    const float* __restrict__ wih,  // (2,24,I)
    const float* __restrict__ whh,  // (2,24,8)
    const float* __restrict__ bih,  // (2,24)
    const float* __restrict__ bhh,  // (2,24)
    float* __restrict__ out)        // (M,64,16), dir writes its 8-half
{
    const int tid = blockIdx.x * 256 + threadIdx.x;
    const int j   = tid & 7;
    const int md  = tid >> 3;
    if (md >= M_SEQ * 2) return;
    const int m = md >> 1, dir = md & 1;

    float wx0[I], wx1[I], wx2[I];
    const float* WI = wih + dir * 24 * I;
#pragma unroll
    for (int k = 0; k < I; ++k) {
        wx0[k] = WI[j * I + k];
        wx1[k] = WI[(8 + j) * I + k];
        wx2[k] = WI[(16 + j) * I + k];
    }
    float w0[8], w1[8], w2[8];
    const float* WH = whh + dir * 192;
#pragma unroll
    for (int k = 0; k < 8; ++k) {
        w0[k] = WH[j * 8 + k];
        w1[k] = WH[(8 + j) * 8 + k];
        w2[k] = WH[(16 + j) * 8 + k];
    }
    const float bx0 = bih[dir*24 + j], bx1 = bih[dir*24 + 8 + j], bx2 = bih[dir*24 + 16 + j];
    const float bh0 = bhh[dir*24 + j], bh1 = bhh[dir*24 + 8 + j], bh2 = bhh[dir*24 + 16 + j];

    const float* xm = x + (size_t)m * TT * I;
    float* om = out + (size_t)m * TT * 16 + dir * 8 + j;

    float h = 0.f;
    for (int tt = 0; tt < TT; ++tt) {
        const int t = dir ? (TT - 1 - tt) : tt;
        float xv[I];
        const float4* xp4 = reinterpret_cast<const float4*>(xm + t * I);
#pragma unroll
        for (int q = 0; q < I / 4; ++q) {
            float4 f = xp4[q];
            xv[4*q] = f.x; xv[4*q+1] = f.y; xv[4*q+2] = f.z; xv[4*q+3] = f.w;
        }
        float xr = bx0, xz = bx1, xn = bx2;
#pragma unroll
        for (int k = 0; k < I; ++k) {
            xr += xv[k] * wx0[k];
            xz += xv[k] * wx1[k];
            xn += xv[k] * wx2[k];
        }
        float gh0 = bh0, gh1 = bh1, gh2 = bh2;
        swz_fma<0>(h, w0, w1, w2, gh0, gh1, gh2);
        float r  = fsig(xr + gh0);
        float z  = fsig(xz + gh1);
        float nn = ftanh(xn + r * gh2);
        h = (1.f - z) * nn + z * h;
        om[t * 16] = h;
    }
}

// ---------------- feat MLP ---------------------------------------------------
__global__ void feat_kernel(const float* __restrict__ gout,
                            const float* __restrict__ l1w, const float* __restrict__ l1b,
                            const float* __restrict__ l2w, const float* __restrict__ l2b,
                            float* __restrict__ feat)
{
    int m = blockIdx.x * blockDim.x + threadIdx.x;
    if (m >= M_SEQ) return;
    const float* xp = gout + (size_t)m * TT * 16 + (TT - 1) * 16;
    float xv[16];
#pragma unroll
    for (int i = 0; i < 16; ++i) xv[i] = xp[i];
    float h1[8];
#pragma unroll
    for (int o = 0; o < 8; ++o) {
        float a = 0.f;
#pragma unroll
        for (int f = 0; f < 16; ++f) a += xv[f] * l1w[o * 16 + f];
        a += l1b[o];
        h1[o] = (a >= 0.f) ? a : 0.2f * a;
    }
#pragma unroll
    for (int o = 0; o < 8; ++o) {
        float a = 0.f;
#pragma unroll
        for (int f = 0; f < 8; ++f) a += h1[f] * l2w[o * 8 + f];
        feat[(size_t)m * 8 + o] = a + l2b[o];
    }
}

// ---------------- adjacency: per row -> (argmax col, adj value v) -----------
__global__ void adj_kernel(const float* __restrict__ feat,
                           const float* __restrict__ tptr,
                           int* __restrict__ colp, float* __restrict__ vp)
{
    const int gw   = (blockIdx.x * blockDim.x + threadIdx.x) >> 6;
    const int lane = threadIdx.x & 63;
    if (gw >= NB * NNODE) return;
    const int b = gw / NNODE;
    const int n = gw - b * NNODE;
    const float T = tptr[0];
    const float* fb = feat + (size_t)b * NNODE * 8;
    float fn[8];
#pragma unroll
    for (int k = 0; k < 8; ++k) fn[k] = fb[(size_t)n * 8 + k];

    float sv[6];
    float mval = -3.0e38f; int midx = 1 << 30;
#pragma unroll
    for (int s = 0; s < 6; ++s) {
        int p = s * 64 + lane;
        float xs = -3.0e38f;
        if (p < NNODE) {
            const float* fp = fb + (size_t)p * 8;
            float d = 0.f;
#pragma unroll
            for (int k = 0; k < 8; ++k) d += fn[k] * fp[k];
            unsigned idx = (unsigned)gw * 360u + (unsigned)p;
            float u   = jax_uniform(idx);
            float gum = -logf(-logf(u + 1e-10f) + 1e-10f);
            xs = (d + gum) / T;
            if (xs > mval) { mval = xs; midx = p; }
        }
        sv[s] = xs;
    }
    for (int off = 32; off > 0; off >>= 1) {   // ties -> smaller index
        float ov = __shfl_xor(mval, off);
        int   oi = __shfl_xor(midx, off);
        if (ov > mval || (ov == mval && oi < midx)) { mval = ov; midx = oi; }
    }
    float ssum = 0.f;
#pragma unroll
    for (int s = 0; s < 6; ++s) {
        int p = s * 64 + lane;
        if (p < NNODE) ssum += expf(sv[s] - mval);
    }
    for (int off = 32; off > 0; off >>= 1) ssum += __shfl_xor(ssum, off);
    if (lane == 0) {
        float ys = 1.0f / ssum;
        float v  = ys + (1.0f - ys);
        if (midx == n) v = 0.0f;
        colp[gw] = midx;
        vp[gw]   = v;
    }
}

// ---------------- DCGRU decode: ONE 64-lane wave per block ------------------
// Lane L owns nodes q*64+L (6 per lane, tail lanes 5). Single wave = lockstep:
// all phase1 LDS reads precede all phase2 writes in program order, so h/o are
// single-buffered and __syncthreads() degenerates to a free 1-wave barrier.
// 6-node ILP per lane covers the LDS gather latency that R9's 3-wave variant
// exposed. Own-node o/h values live in registers (4 gathers/node, not 8).
__device__ __forceinline__ void dstep(
    float* __restrict__ s_o, float (* __restrict__ s_h)[NNODE],
    float* __restrict__ s_rh,
    const float* __restrict__ Wg, const float* __restrict__ Bg,
    const float* __restrict__ Wc, const float* __restrict__ Cb,
    const bool* act, const int* nn, const int* c1, const int* c2,
    const float* v, const float* vv,
    float (*h)[NQ], float* oreg)
{
#pragma unroll
    for (int l = 0; l < 3; ++l) {
        const float* W = Wg + l * 12;
        const float* C = Wc + l * 6;
        const float bgr = Bg[2 * l], bgu = Bg[2 * l + 1], cb = Cb[l];
        float f0[NQ], f1[NQ], f2[NQ], uu[NQ], rh[NQ];
        __syncthreads();   // free (1 wave); orders s_o/s_h writes vs reads
#pragma unroll
        for (int q = 0; q < NQ; ++q) {
            if (!act[q]) continue;
            float o1 = s_o[c1[q]], o2 = s_o[c2[q]];
            float hg1 = s_h[l][c1[q]], hg2 = s_h[l][c2[q]];
            float ho = h[l][q], oo = oreg[q];
            float F1 = v[q] * o1, F2 = vv[q] * o2 - oo;
            float F4 = v[q] * hg1, F5 = vv[q] * hg2 - ho;
            float r = fsigd(oo*W[0] + F1*W[2] + F2*W[4] + ho*W[6] + F4*W[8] + F5*W[10] + bgr);
            float u = fsigd(oo*W[1] + F1*W[3] + F2*W[5] + ho*W[7] + F4*W[9] + F5*W[11] + bgu);
            float rhq = r * ho;
            s_rh[nn[q]] = rhq;
            f0[q] = oo; f1[q] = F1; f2[q] = F2; uu[q] = u; rh[q] = rhq;
        }
        __syncthreads();   // rh visible
#pragma unroll
        for (int q = 0; q < NQ; ++q) {
            if (!act[q]) continue;
            float r1 = s_rh[c1[q]], r2 = s_rh[c2[q]];
            float cnd = ftanhd(f0[q]*C[0] + f1[q]*C[1] + f2[q]*C[2]
                               + rh[q]*C[3] + (v[q]*r1)*C[4]
                               + (vv[q]*r2 - rh[q])*C[5] + cb);
            float hn = uu[q] * h[l][q] + (1.f - uu[q]) * cnd;
            h[l][q] = hn;
            s_h[l][nn[q]] = hn;
            oreg[q] = hn;
            if (l < 2) s_o[nn[q]] = hn;
        }
    }
}

__global__ __launch_bounds__(64) void decode_kernel(
    const float* __restrict__ rec,   // (B, N, T)
    const int*   __restrict__ colp, const float* __restrict__ vp,
    const float* __restrict__ egw, const float* __restrict__ egb,
    const float* __restrict__ ecw, const float* __restrict__ ecb,
    const float* __restrict__ dgw, const float* __restrict__ dgb,
    const float* __restrict__ dcw, const float* __restrict__ dcb,
    const float* __restrict__ pw,  const float* __restrict__ pb,
    float* __restrict__ outp)        // (B, N, T)
{
    __shared__ float s_o[NNODE];
    __shared__ float s_h[3][NNODE];
    __shared__ float s_rh[NNODE];
    __shared__ float s_v[NNODE];
    __shared__ int   s_c[NNODE];

    const int b = blockIdx.x;
    const int L = threadIdx.x;

    bool act[NQ]; int nn[NQ];
#pragma unroll
    for (int q = 0; q < NQ; ++q) {
        nn[q]  = q * 64 + L;
        act[q] = nn[q] < NNODE;
        if (act[q]) {
            s_c[nn[q]] = colp[b * NNODE + nn[q]];
            s_v[nn[q]] = vp[b * NNODE + nn[q]];
            s_h[0][nn[q]] = 0.f; s_h[1][nn[q]] = 0.f; s_h[2][nn[q]] = 0.f;
        }
    }
    __syncthreads();
    int c1[NQ], c2[NQ]; float v[NQ], vv[NQ];
#pragma unroll
    for (int q = 0; q < NQ; ++q) {
        if (act[q]) {
            c1[q] = s_c[nn[q]]; c2[q] = s_c[c1[q]];
            v[q]  = s_v[nn[q]]; vv[q] = 2.f * v[q] * s_v[c1[q]];
        } else { c1[q] = 0; c2[q] = 0; v[q] = 0.f; vv[q] = 0.f; }
    }
    const float projw = pw[0], projb = pb[0];
    float h[3][NQ];
#pragma unroll
    for (int l = 0; l < 3; ++l)
#pragma unroll
        for (int q = 0; q < NQ; ++q) h[l][q] = 0.f;
    float oreg[NQ], in[NQ], nx[NQ];

    // encoder, one-step input prefetch
#pragma unroll
    for (int q = 0; q < NQ; ++q)
        in[q] = act[q] ? rec[((size_t)b * NNODE + nn[q]) * TT + 0] : 0.f;
    for (int t = 0; t < TT; ++t) {
#pragma unroll
        for (int q = 0; q < NQ; ++q)
            nx[q] = (act[q] && t + 1 < TT) ? rec[((size_t)b * NNODE + nn[q]) * TT + t + 1] : 0.f;
#pragma unroll
        for (int q = 0; q < NQ; ++q) {
            if (act[q]) s_o[nn[q]] = in[q];
            oreg[q] = in[q];
        }
        dstep(s_o, s_h, s_rh, egw, egb, ecw, ecb, act, nn, c1, c2, v, vv, h, oreg);
#pragma unroll
        for (int q = 0; q < NQ; ++q) in[q] = nx[q];
    }
    // decoder, feedback = proj
#pragma unroll
    for (int q = 0; q < NQ; ++q) in[q] = 0.f;
    for (int t = 0; t < TT; ++t) {
#pragma unroll
        for (int q = 0; q < NQ; ++q) {
            if (act[q]) s_o[nn[q]] = in[q];
            oreg[q] = in[q];
        }
        dstep(s_o, s_h, s_rh, dgw, dgb, dcw, dcb, act, nn, c1, c2, v, vv, h, oreg);
#pragma unroll
        for (int q = 0; q < NQ; ++q) {
            float pj = oreg[q] * projw + projb;
            if (act[q]) outp[((size_t)b * NNODE + nn[q]) * TT + t] = pj;
            in[q] = pj;
        }
    }
}

// ---------------- host launcher ---------------------------------------------
extern "C" void kernel_launch(void* const* d_in, const int* in_sizes, int n_in,
                              void* d_out, int out_size, void* d_ws, size_t ws_size,
                              hipStream_t stream)
{
    (void)in_sizes; (void)n_in; (void)out_size; (void)ws_size;
    const float* full_seq = (const float*)d_in[0];   // (M,64,8)
    const float* rec_seq  = (const float*)d_in[1];   // (32,360,64)
    const float* temp     = (const float*)d_in[3];
    const float* g0wih    = (const float*)d_in[4];
    const float* g0whh    = (const float*)d_in[5];
    const float* g0bih    = (const float*)d_in[6];
    const float* g0bhh    = (const float*)d_in[7];
    const float* gwih     = (const float*)d_in[8];   // (3,2,24,16)
    const float* gwhh     = (const float*)d_in[9];   // (3,2,24,8)
    const float* gbih     = (const float*)d_in[10];
    const float* gbhh     = (const float*)d_in[11];
    const float* l1w      = (const float*)d_in[12];
    const float* l1b      = (const float*)d_in[13];
    const float* l2w      = (const float*)d_in[14];
    const float* l2b      = (const float*)d_in[15];
    const float* enc_gw   = (const float*)d_in[16];
    const float* enc_gb   = (const float*)d_in[17];
    const float* enc_cw   = (const float*)d_in[18];
    const float* enc_cb   = (const float*)d_in[19];
    const float* dec_gw   = (const float*)d_in[20];
    const float* dec_gb   = (const float*)d_in[21];
    const float* dec_cw   = (const float*)d_in[22];
    const float* dec_cb   = (const float*)d_in[23];
    const float* proj_w   = (const float*)d_in[24];
    const float* proj_b   = (const float*)d_in[25];
    float* outp = (float*)d_out;

    // ws: small-first; bufA+bufB ping-pong = 94.85 MB total (proven size)
    float* ws   = (float*)d_ws;
    float* feat = ws;                                     // (M,8)
    float* vbuf = feat + (size_t)M_SEQ * 8;               // (M,)
    int*   cbuf = (int*)(vbuf + M_SEQ);                   // (M,)
    float* bufA = (float*)(cbuf + M_SEQ);                 // (M,64,16)
    float* bufB = bufA + (size_t)M_SEQ * TT * 16;         // (M,64,16)

    const int ggru = (M_SEQ * 2 * 8) / 256;   // 720 blocks
    gru_fused<8><<<ggru, 256, 0, stream>>>(full_seq, g0wih, g0whh, g0bih, g0bhh, bufA);
    gru_fused<16><<<ggru, 256, 0, stream>>>(bufA, gwih + 0 * 768, gwhh + 0 * 384,
                                            gbih + 0 * 48, gbhh + 0 * 48, bufB);
    gru_fused<16><<<ggru, 256, 0, stream>>>(bufB, gwih + 1 * 768, gwhh + 1 * 384,
                                            gbih + 1 * 48, gbhh + 1 * 48, bufA);
    gru_fused<16><<<ggru, 256, 0, stream>>>(bufA, gwih + 2 * 768, gwhh + 2 * 384,
                                            gbih + 2 * 48, gbhh + 2 * 48, bufB);
    feat_kernel<<<M_SEQ / 256, 256, 0, stream>>>(bufB, l1w, l1b, l2w, l2b, feat);
    adj_kernel<<<(NB * NNODE) / 4, 256, 0, stream>>>(feat, temp, cbuf, vbuf);
    decode_kernel<<<NB, 64, 0, stream>>>(rec_seq, cbuf, vbuf,
                                         enc_gw, enc_gb, enc_cw, enc_cb,
                                         dec_gw, dec_gb, dec_cw, dec_cb,
                                         proj_w, proj_b, outp);
}

// Round 11
// 632.660 us; speedup vs baseline: 1.8827x; 1.8827x over previous
//
#include <hip/hip_runtime.h>
#include <math.h>

#define M_SEQ 11520   // B*N
#define NNODE 360
#define NB    32
#define TT    64

// GRU/feat/adj path: libm-accurate (feeds the precision-fragile argmax).
__device__ __forceinline__ float fsig(float x)  { return 1.0f / (1.0f + expf(-x)); }
__device__ __forceinline__ float ftanh(float x) { return tanhf(x); }
// Decode path: post-argmax, fast hardware exp (absmax invariant across R7/R9/R10).
__device__ __forceinline__ float fsigd(float x)  { return 1.0f / (1.0f + __expf(-x)); }
__device__ __forceinline__ float ftanhd(float x) { return 1.0f - 2.0f / (__expf(2.0f * x) + 1.0f); }

// ---------------- JAX threefry2x32, key=(0,42), partitionable, bits=y0^y1 ----
__device__ __forceinline__ unsigned rotl32(unsigned x, int n) { return (x << n) | (x >> (32 - n)); }

__device__ __forceinline__ void tf2x32(unsigned& x0, unsigned& x1)
{
    const unsigned k0 = 0u, k1 = 42u, k2 = 0u ^ 42u ^ 0x1BD11BDAu;
    x0 += k0; x1 += k1;
#define R4(a,b,c,d) \
    x0 += x1; x1 = rotl32(x1,a); x1 ^= x0; \
    x0 += x1; x1 = rotl32(x1,b); x1 ^= x0; \
    x0 += x1; x1 = rotl32(x1,c); x1 ^= x0; \
    x0 += x1; x1 = rotl32(x1,d); x1 ^= x0;
    R4(13,15,26,6)   x0 += k1; x1 += k2 + 1u;
    R4(17,29,16,24)  x0 += k2; x1 += k0 + 2u;
    R4(13,15,26,6)   x0 += k0; x1 += k1 + 3u;
    R4(17,29,16,24)  x0 += k1; x1 += k2 + 4u;
    R4(13,15,26,6)   x0 += k2; x1 += k0 + 5u;
#undef R4
}

__device__ __forceinline__ float jax_uniform(unsigned idx)
{
    unsigned x0 = 0u, x1 = idx;
    tf2x32(x0, x1);
    unsigned bits = x0 ^ x1;          // VERIFIED R5
    return __uint_as_float((bits >> 9) | 0x3f800000u) - 1.0f;
}

// broadcast within aligned 8-lane group via static-pattern ds_swizzle.
template<int K>
__device__ __forceinline__ void swz_fma(float h, const float* w0, const float* w1,
                                        const float* w2, float& g0, float& g1, float& g2)
{
    float hk = __int_as_float(
        __builtin_amdgcn_ds_swizzle(__float_as_int(h), (K << 5) | 0x18));
    g0 += hk * w0[K];
    g1 += hk * w1[K];
    g2 += hk * w2[K];
    if constexpr (K < 7)
        swz_fma<K + 1>(h, w0, w1, w2, g0, g1, g2);
}

// ---------------- fused bidirectional GRU layer -----------------------------
template<int I>
__global__ __launch_bounds__(256) void gru_fused(
    const float* __restrict__ x,    // (M,64,I)
    const float* __restrict__ wih,  // (2,24,I)
    const float* __restrict__ whh,  // (2,24,8)
    const float* __restrict__ bih,  // (2,24)
    const float* __restrict__ bhh,  // (2,24)
    float* __restrict__ out)        // (M,64,16), dir writes its 8-half
{
    const int tid = blockIdx.x * 256 + threadIdx.x;
    const int j   = tid & 7;
    const int md  = tid >> 3;
    if (md >= M_SEQ * 2) return;
    const int m = md >> 1, dir = md & 1;

    float wx0[I], wx1[I], wx2[I];
    const float* WI = wih + dir * 24 * I;
#pragma unroll
    for (int k = 0; k < I; ++k) {
        wx0[k] = WI[j * I + k];
        wx1[k] = WI[(8 + j) * I + k];
        wx2[k] = WI[(16 + j) * I + k];
    }
    float w0[8], w1[8], w2[8];
    const float* WH = whh + dir * 192;
#pragma unroll
    for (int k = 0; k < 8; ++k) {
        w0[k] = WH[j * 8 + k];
        w1[k] = WH[(8 + j) * 8 + k];
        w2[k] = WH[(16 + j) * 8 + k];
    }
    const float bx0 = bih[dir*24 + j], bx1 = bih[dir*24 + 8 + j], bx2 = bih[dir*24 + 16 + j];
    const float bh0 = bhh[dir*24 + j], bh1 = bhh[dir*24 + 8 + j], bh2 = bhh[dir*24 + 16 + j];

    const float* xm = x + (size_t)m * TT * I;
    float* om = out + (size_t)m * TT * 16 + dir * 8 + j;

    float h = 0.f;
    for (int tt = 0; tt < TT; ++tt) {
        const int t = dir ? (TT - 1 - tt) : tt;
        float xv[I];
        const float4* xp4 = reinterpret_cast<const float4*>(xm + t * I);
#pragma unroll
        for (int q = 0; q < I / 4; ++q) {
            float4 f = xp4[q];
            xv[4*q] = f.x; xv[4*q+1] = f.y; xv[4*q+2] = f.z; xv[4*q+3] = f.w;
        }
        float xr = bx0, xz = bx1, xn = bx2;
#pragma unroll
        for (int k = 0; k < I; ++k) {
            xr += xv[k] * wx0[k];
            xz += xv[k] * wx1[k];
            xn += xv[k] * wx2[k];
        }
        float gh0 = bh0, gh1 = bh1, gh2 = bh2;
        swz_fma<0>(h, w0, w1, w2, gh0, gh1, gh2);
        float r  = fsig(xr + gh0);
        float z  = fsig(xz + gh1);
        float nn = ftanh(xn + r * gh2);
        h = (1.f - z) * nn + z * h;
        om[t * 16] = h;
    }
}

// ---------------- feat MLP ---------------------------------------------------
__global__ void feat_kernel(const float* __restrict__ gout,
                            const float* __restrict__ l1w, const float* __restrict__ l1b,
                            const float* __restrict__ l2w, const float* __restrict__ l2b,
                            float* __restrict__ feat)
{
    int m = blockIdx.x * blockDim.x + threadIdx.x;
    if (m >= M_SEQ) return;
    const float* xp = gout + (size_t)m * TT * 16 + (TT - 1) * 16;
    float xv[16];
#pragma unroll
    for (int i = 0; i < 16; ++i) xv[i] = xp[i];
    float h1[8];
#pragma unroll
    for (int o = 0; o < 8; ++o) {
        float a = 0.f;
#pragma unroll
        for (int f = 0; f < 16; ++f) a += xv[f] * l1w[o * 16 + f];
        a += l1b[o];
        h1[o] = (a >= 0.f) ? a : 0.2f * a;
    }
#pragma unroll
    for (int o = 0; o < 8; ++o) {
        float a = 0.f;
#pragma unroll
        for (int f = 0; f < 8; ++f) a += h1[f] * l2w[o * 8 + f];
        feat[(size_t)m * 8 + o] = a + l2b[o];
    }
}

// ---------------- adjacency: per row -> (argmax col, adj value v) -----------
__global__ void adj_kernel(const float* __restrict__ feat,
                           const float* __restrict__ tptr,
                           int* __restrict__ colp, float* __restrict__ vp)
{
    const int gw   = (blockIdx.x * blockDim.x + threadIdx.x) >> 6;
    const int lane = threadIdx.x & 63;
    if (gw >= NB * NNODE) return;
    const int b = gw / NNODE;
    const int n = gw - b * NNODE;
    const float T = tptr[0];
    const float* fb = feat + (size_t)b * NNODE * 8;
    float fn[8];
#pragma unroll
    for (int k = 0; k < 8; ++k) fn[k] = fb[(size_t)n * 8 + k];

    float sv[6];
    float mval = -3.0e38f; int midx = 1 << 30;
#pragma unroll
    for (int s = 0; s < 6; ++s) {
        int p = s * 64 + lane;
        float xs = -3.0e38f;
        if (p < NNODE) {
            const float* fp = fb + (size_t)p * 8;
            float d = 0.f;
#pragma unroll
            for (int k = 0; k < 8; ++k) d += fn[k] * fp[k];
            unsigned idx = (unsigned)gw * 360u + (unsigned)p;
            float u   = jax_uniform(idx);
            float gum = -logf(-logf(u + 1e-10f) + 1e-10f);
            xs = (d + gum) / T;
            if (xs > mval) { mval = xs; midx = p; }
        }
        sv[s] = xs;
    }
    for (int off = 32; off > 0; off >>= 1) {   // ties -> smaller index
        float ov = __shfl_xor(mval, off);
        int   oi = __shfl_xor(midx, off);
        if (ov > mval || (ov == mval && oi < midx)) { mval = ov; midx = oi; }
    }
    float ssum = 0.f;
#pragma unroll
    for (int s = 0; s < 6; ++s) {
        int p = s * 64 + lane;
        if (p < NNODE) ssum += expf(sv[s] - mval);
    }
    for (int off = 32; off > 0; off >>= 1) ssum += __shfl_xor(ssum, off);
    if (lane == 0) {
        float ys = 1.0f / ssum;
        float v  = ys + (1.0f - ys);
        if (midx == n) v = 0.0f;
        colp[gw] = midx;
        vp[gw]   = v;
    }
}

// ---------------- DCGRU 3-layer step: R6-proven structure --------------------
// 2 barriers/layer, 1 node/thread, 6 waves. Own-node o/h kept in registers
// (4 LDS gathers/phase-A instead of 6); fast __expf (post-argmax, safe).
// Returns the layer-2 h (decoder feedback).
__device__ __forceinline__ float run3(
    float* __restrict__ s_o, float (* __restrict__ s_h)[NNODE],
    float* __restrict__ s_rh,
    const float* __restrict__ Wg, const float* __restrict__ Bg,
    const float* __restrict__ Wc, const float* __restrict__ Cb,
    bool act, int n, int c1, int c2, float v, float vv,
    float* __restrict__ hreg, float o)
{
#pragma unroll
    for (int l = 0; l < 3; ++l) {
        __syncthreads();   // s_o / s_h[l] ready for gathers
        float oc1 = 0.f, oc2 = 0.f, hc1 = 0.f, hc2 = 0.f;
        if (act) {
            oc1 = s_o[c1]; oc2 = s_o[c2];
            hc1 = s_h[l][c1]; hc2 = s_h[l][c2];
        }
        const float hn = hreg[l];
        const float* W = Wg + l * 12;
        const float bgr = Bg[2 * l], bgu = Bg[2 * l + 1];
        float f1 = v * oc1, f2 = vv * oc2 - o;
        float f4 = v * hc1, f5 = vv * hc2 - hn;
        float r = fsigd(o*W[0] + f1*W[2] + f2*W[4] + hn*W[6] + f4*W[8] + f5*W[10] + bgr);
        float u = fsigd(o*W[1] + f1*W[3] + f2*W[5] + hn*W[7] + f4*W[9] + f5*W[11] + bgu);
        float rhn = r * hn;
        if (act) s_rh[n] = rhn;
        __syncthreads();   // rh visible
        float rhc1 = 0.f, rhc2 = 0.f;
        if (act) { rhc1 = s_rh[c1]; rhc2 = s_rh[c2]; }
        const float* C = Wc + l * 6;
        float cnd = ftanhd(o*C[0] + f1*C[1] + f2*C[2]
                           + rhn*C[3] + (v*rhc1)*C[4] + (vv*rhc2 - rhn)*C[5] + Cb[l]);
        float hnew = u * hn + (1.f - u) * cnd;
        hreg[l] = hnew;
        if (act) { s_h[l][n] = hnew; if (l < 2) s_o[n] = hnew; }
        o = hnew;
    }
    return o;
}

__global__ __launch_bounds__(384) void decode_kernel(
    const float* __restrict__ rec,   // (B, N, T)
    const int*   __restrict__ colp, const float* __restrict__ vp,
    const float* __restrict__ egw, const float* __restrict__ egb,
    const float* __restrict__ ecw, const float* __restrict__ ecb,
    const float* __restrict__ dgw, const float* __restrict__ dgb,
    const float* __restrict__ dcw, const float* __restrict__ dcb,
    const float* __restrict__ pw,  const float* __restrict__ pb,
    float* __restrict__ outp)        // (B, N, T)
{
    __shared__ float s_o[NNODE];
    __shared__ float s_h[3][NNODE];
    __shared__ float s_rh[NNODE];
    __shared__ float s_v[NNODE];
    __shared__ int   s_c[NNODE];
    __shared__ float s_egw[36], s_egb[6], s_ecw[18], s_ecb[3];
    __shared__ float s_dgw[36], s_dgb[6], s_dcw[18], s_dcb[3];

    const int b = blockIdx.x;
    const int n = threadIdx.x;
    if (n < 36) { s_egw[n] = egw[n]; s_dgw[n] = dgw[n]; }
    if (n < 6)  { s_egb[n] = egb[n]; s_dgb[n] = dgb[n]; }
    if (n < 18) { s_ecw[n] = ecw[n]; s_dcw[n] = dcw[n]; }
    if (n < 3)  { s_ecb[n] = ecb[n]; s_dcb[n] = dcb[n]; }
    const bool act = n < NNODE;
    if (act) {
        s_c[n] = colp[b * NNODE + n];
        s_v[n] = vp[b * NNODE + n];
        s_h[0][n] = 0.f; s_h[1][n] = 0.f; s_h[2][n] = 0.f;
    }
    __syncthreads();
    int c1 = 0, c2 = 0; float v = 0.f, vv = 0.f;
    if (act) {
        c1 = s_c[n];
        c2 = s_c[c1];
        v  = s_v[n];
        vv = 2.f * v * s_v[c1];
    }
    const float projw = pw[0], projb = pb[0];
    float hreg[3] = {0.f, 0.f, 0.f};

    // encoder, one-step input prefetch
    float inp = act ? rec[((size_t)b * NNODE + n) * TT + 0] : 0.f;
    for (int t = 0; t < TT; ++t) {
        float nx = (act && t + 1 < TT) ? rec[((size_t)b * NNODE + n) * TT + t + 1] : 0.f;
        if (act) s_o[n] = inp;
        run3(s_o, s_h, s_rh, s_egw, s_egb, s_ecw, s_ecb, act, n, c1, c2, v, vv, hreg, inp);
        inp = nx;
    }
    // decoder, feedback = proj
    float dinp = 0.f;
    for (int t = 0; t < TT; ++t) {
        if (act) s_o[n] = dinp;
        float h3 = run3(s_o, s_h, s_rh, s_dgw, s_dgb, s_dcw, s_dcb,
                        act, n, c1, c2, v, vv, hreg, dinp);
        float proj = h3 * projw + projb;
        if (act) outp[((size_t)b * NNODE + n) * TT + t] = proj;
        dinp = proj;
    }
}

// ---------------- host launcher ---------------------------------------------
extern "C" void kernel_launch(void* const* d_in, const int* in_sizes, int n_in,
                              void* d_out, int out_size, void* d_ws, size_t ws_size,
                              hipStream_t stream)
{
    (void)in_sizes; (void)n_in; (void)out_size; (void)ws_size;
    const float* full_seq = (const float*)d_in[0];   // (M,64,8)
    const float* rec_seq  = (const float*)d_in[1];   // (32,360,64)
    const float* temp     = (const float*)d_in[3];
    const float* g0wih    = (const float*)d_in[4];
    const float* g0whh    = (const float*)d_in[5];
    const float* g0bih    = (const float*)d_in[6];
    const float* g0bhh    = (const float*)d_in[7];
    const float* gwih     = (const float*)d_in[8];   // (3,2,24,16)
    const float* gwhh     = (const float*)d_in[9];   // (3,2,24,8)
    const float* gbih     = (const float*)d_in[10];
    const float* gbhh     = (const float*)d_in[11];
    const float* l1w      = (const float*)d_in[12];
    const float* l1b      = (const float*)d_in[13];
    const float* l2w      = (const float*)d_in[14];
    const float* l2b      = (const float*)d_in[15];
    const float* enc_gw   = (const float*)d_in[16];
    const float* enc_gb   = (const float*)d_in[17];
    const float* enc_cw   = (const float*)d_in[18];
    const float* enc_cb   = (const float*)d_in[19];
    const float* dec_gw   = (const float*)d_in[20];
    const float* dec_gb   = (const float*)d_in[21];
    const float* dec_cw   = (const float*)d_in[22];
    const float* dec_cb   = (const float*)d_in[23];
    const float* proj_w   = (const float*)d_in[24];
    const float* proj_b   = (const float*)d_in[25];
    float* outp = (float*)d_out;

    // ws: small-first; bufA+bufB ping-pong = 94.85 MB total (proven size)
    float* ws   = (float*)d_ws;
    float* feat = ws;                                     // (M,8)
    float* vbuf = feat + (size_t)M_SEQ * 8;               // (M,)
    int*   cbuf = (int*)(vbuf + M_SEQ);                   // (M,)
    float* bufA = (float*)(cbuf + M_SEQ);                 // (M,64,16)
    float* bufB = bufA + (size_t)M_SEQ * TT * 16;         // (M,64,16)

    const int ggru = (M_SEQ * 2 * 8) / 256;   // 720 blocks
    gru_fused<8><<<ggru, 256, 0, stream>>>(full_seq, g0wih, g0whh, g0bih, g0bhh, bufA);
    gru_fused<16><<<ggru, 256, 0, stream>>>(bufA, gwih + 0 * 768, gwhh + 0 * 384,
                                            gbih + 0 * 48, gbhh + 0 * 48, bufB);
    gru_fused<16><<<ggru, 256, 0, stream>>>(bufB, gwih + 1 * 768, gwhh + 1 * 384,
                                            gbih + 1 * 48, gbhh + 1 * 48, bufA);
    gru_fused<16><<<ggru, 256, 0, stream>>>(bufA, gwih + 2 * 768, gwhh + 2 * 384,
                                            gbih + 2 * 48, gbhh + 2 * 48, bufB);
    feat_kernel<<<M_SEQ / 256, 256, 0, stream>>>(bufB, l1w, l1b, l2w, l2b, feat);
    adj_kernel<<<(NB * NNODE) / 4, 256, 0, stream>>>(feat, temp, cbuf, vbuf);
    decode_kernel<<<NB, 384, 0, stream>>>(rec_seq, cbuf, vbuf,
                                          enc_gw, enc_gb, enc_cw, enc_cb,
                                          dec_gw, dec_gb, dec_cw, dec_cb,
                                          proj_w, proj_b, outp);
}